// Round 1
// baseline (237.591 us; speedup 1.0000x reference)
//
#include <hip/hip_runtime.h>
#include <hip/hip_bf16.h>

#define HW    3136
#define C_IN  256
#define CR    64
#define G_    16
#define GC_   16
#define IMGH  56
#define IMGW  56
#define EPSV  1e-5f

typedef __bf16 bf16x8 __attribute__((ext_vector_type(8)));
typedef float  f32x4  __attribute__((ext_vector_type(4)));

static __device__ __forceinline__ unsigned short f2bf(float f) {
    union { float f; unsigned u; } v; v.f = f;
    unsigned r = (v.u + 0x7FFFu + ((v.u >> 16) & 1u)) >> 16;   // RNE
    return (unsigned short)r;
}

// ---------------------------------------------------------------------------
// Kernel 1: xrT[b*HW+l][o] = bf16( relu( BN( W_reduce @ x + b_reduce ) ) )
// grid (98, 4), block 128.  blockIdx.y = o-quarter (16 outputs) -> W reads
// are block-uniform => scalar loads.
// ---------------------------------------------------------------------------
__global__ __launch_bounds__(128) void k_reduce(
    const float* __restrict__ x,  const float* __restrict__ Wr,
    const float* __restrict__ br, const float* __restrict__ gamma,
    const float* __restrict__ beta, const float* __restrict__ mean,
    const float* __restrict__ var, unsigned short* __restrict__ xrT)
{
    int t  = threadIdx.x;
    int gl = blockIdx.x * 128 + t;          // 0..12543 global pixel
    int q  = blockIdx.y;                    // output-channel quarter
    int b  = gl / HW;
    int l  = gl - b * HW;
    const float* xb = x + (size_t)b * C_IN * HW + l;
    const float* Wq = Wr + q * 16 * C_IN;

    float acc[16];
#pragma unroll
    for (int i = 0; i < 16; ++i) acc[i] = 0.f;

#pragma unroll 4
    for (int c = 0; c < C_IN; ++c) {
        float xv = xb[(size_t)c * HW];
#pragma unroll
        for (int i = 0; i < 16; ++i)
            acc[i] += Wq[i * C_IN + c] * xv;
    }

    union { unsigned short s[16]; uint4 v[2]; } pk;
#pragma unroll
    for (int i = 0; i < 16; ++i) {
        int o = q * 16 + i;
        float s  = gamma[o] * rsqrtf(var[o] + EPSV);
        float vv = (acc[i] + br[o] - mean[o]) * s + beta[o];
        vv = fmaxf(vv, 0.f);
        pk.s[i] = f2bf(vv);
    }
    uint4* dst = (uint4*)(xrT + (size_t)gl * 64 + q * 16);
    dst[0] = pk.v[0];
    dst[1] = pk.v[1];
}

// ---------------------------------------------------------------------------
// Kernel 2: per (b, g, h-row):
//   Phase A: kern[49][56] = Wspan_g[49][64] @ xr[64][56] + b_span   (bf16 MFMA)
//   Phase B: out[c][w] = sum_k kern[k][w] * x[g*16+c][h+kh-3][w+kw-3]
// grid (56, 16, 4), block 256.
// ---------------------------------------------------------------------------
__global__ __launch_bounds__(256) void k_invol(
    const float* __restrict__ x, const unsigned short* __restrict__ xrT,
    const float* __restrict__ Wspan, const float* __restrict__ bspan,
    float* __restrict__ out)
{
    __shared__ __align__(16) unsigned short s_xr[64][72];  // [pixel][c] bf16, pad rows 56..63 = 0
    __shared__ __align__(16) unsigned short s_ws[64][72];  // [k_out][c]  bf16, pad rows 49..63 = 0
    __shared__ float s_kern[49][57];                       // [k_out][w]
    __shared__ float s_x[GC_ * 7 * 62];                    // [c][row -3..3][col -3..58]

    int h = blockIdx.x, g = blockIdx.y, b = blockIdx.z;
    int t = threadIdx.x;

    // ---- stage xr row: 56 px x 64c bf16 = 56 x 128B contiguous ----
    {
        const uint4* src = (const uint4*)(xrT + ((size_t)b * HW + h * IMGW) * 64);
        for (int i = t; i < 512; i += 256) {               // 64 rows x 8 chunks
            int w = i >> 3, j = i & 7;
            uint4 v = make_uint4(0u, 0u, 0u, 0u);
            if (w < IMGW) v = src[w * 8 + j];
            *(uint4*)&s_xr[w][j * 8] = v;
        }
    }
    // ---- stage W_span group chunk: 49x64 fp32 contiguous -> bf16 ----
    {
        const float* wsg = Wspan + (size_t)g * 49 * 64;
        for (int i = t; i < 64 * 64; i += 256) {
            int k = i >> 6;
            s_ws[k][i & 63] = (k < 49) ? f2bf(wsg[i]) : (unsigned short)0;
        }
    }
    // ---- stage x tile: 16 ch x 7 rows x 62 cols, zero-padded borders ----
    {
        const float* xg = x + (size_t)(b * C_IN + g * GC_) * HW;
        for (int i = t; i < GC_ * 7 * 62; i += 256) {
            int c   = i / 434;              // 7*62
            int rem = i - c * 434;
            int r   = rem / 62;
            int wc  = rem - r * 62 - 3;
            int hr  = h + r - 3;
            float v = 0.f;
            if (hr >= 0 && hr < IMGH && wc >= 0 && wc < IMGW)
                v = xg[(size_t)c * HW + hr * IMGW + wc];
            s_x[i] = v;
        }
    }
    __syncthreads();

    // ---- Phase A: MFMA  kern = Wspan_g @ xr ----
    {
        int wv = t >> 6, lane = t & 63;
        int ln = lane & 15, quad = lane >> 4;
        int m0 = wv * 16;                                  // k_out tile base
        f32x4 acc[4];
#pragma unroll
        for (int nt = 0; nt < 4; ++nt) acc[nt] = (f32x4){0.f, 0.f, 0.f, 0.f};

#pragma unroll
        for (int ks = 0; ks < 2; ++ks) {
            int c0 = ks * 32;
            bf16x8 a = *(const bf16x8*)&s_ws[m0 + ln][c0 + quad * 8];
#pragma unroll
            for (int nt = 0; nt < 4; ++nt) {
                bf16x8 bb = *(const bf16x8*)&s_xr[nt * 16 + ln][c0 + quad * 8];
                acc[nt] = __builtin_amdgcn_mfma_f32_16x16x32_bf16(a, bb, acc[nt], 0, 0, 0);
            }
        }
        // C/D layout: col = lane&15, row = quad*4 + reg   [measured m89/m91]
#pragma unroll
        for (int nt = 0; nt < 4; ++nt) {
            int w = nt * 16 + ln;
#pragma unroll
            for (int r = 0; r < 4; ++r) {
                int ko = m0 + quad * 4 + r;
                if (ko < 49 && w < IMGW)
                    s_kern[ko][w] = acc[nt][r] + bspan[g * 49 + ko];
            }
        }
    }
    __syncthreads();

    // ---- Phase B: 49-tap involution, 224 threads = 56 w x 4 channel-quads ----
    if (t < 224) {
        int w = t % 56, cq = t / 56;
        const float* sx = s_x + cq * 4 * 434;
        float a0 = 0.f, a1 = 0.f, a2 = 0.f, a3 = 0.f;
#pragma unroll
        for (int r = 0; r < 7; ++r) {
#pragma unroll
            for (int dw = 0; dw < 7; ++dw) {
                float kv = s_kern[r * 7 + dw][w];
                int  xi  = r * 62 + w + dw;
                a0 += kv * sx[xi];
                a1 += kv * sx[xi + 434];
                a2 += kv * sx[xi + 2 * 434];
                a3 += kv * sx[xi + 3 * 434];
            }
        }
        float* og = out + (size_t)(b * C_IN + g * GC_ + cq * 4) * HW + h * IMGW + w;
        og[0]      = a0;
        og[HW]     = a1;
        og[2 * HW] = a2;
        og[3 * HW] = a3;
    }
}

// ---------------------------------------------------------------------------
extern "C" void kernel_launch(void* const* d_in, const int* in_sizes, int n_in,
                              void* d_out, int out_size, void* d_ws, size_t ws_size,
                              hipStream_t stream)
{
    const float* x   = (const float*)d_in[0];
    const float* Wr  = (const float*)d_in[1];
    const float* br  = (const float*)d_in[2];
    const float* gm  = (const float*)d_in[3];
    const float* bt  = (const float*)d_in[4];
    const float* mn  = (const float*)d_in[5];
    const float* vr  = (const float*)d_in[6];
    const float* Ws  = (const float*)d_in[7];
    const float* bs  = (const float*)d_in[8];
    float* out = (float*)d_out;

    unsigned short* xrT = (unsigned short*)d_ws;   // 12544 x 64 bf16 = 1.6 MB

    k_reduce<<<dim3(98, 4), 128, 0, stream>>>(x, Wr, br, gm, bt, mn, vr, xrT);
    k_invol<<<dim3(IMGW, G_, 4), 256, 0, stream>>>(x, xrT, Ws, bs, out);
}

// Round 2
// 163.701 us; speedup vs baseline: 1.4514x; 1.4514x over previous
//
#include <hip/hip_runtime.h>
#include <hip/hip_bf16.h>

#define HW    3136
#define C_IN  256
#define CR    64
#define G_    16
#define GC_   16
#define IMGH  56
#define IMGW  56
#define EPSV  1e-5f

typedef __bf16 bf16x8 __attribute__((ext_vector_type(8)));
typedef float  f32x4  __attribute__((ext_vector_type(4)));

static __device__ __forceinline__ unsigned short f2bf(float f) {
    union { float f; unsigned u; } v; v.f = f;
    unsigned r = (v.u + 0x7FFFu + ((v.u >> 16) & 1u)) >> 16;   // RNE
    return (unsigned short)r;
}

// ---------------------------------------------------------------------------
// Kernel 1: xrT[pix][o] = bf16( relu( BN( W_reduce @ x + b_reduce ) ) )
// grid (98, 8), block 128. blockIdx.y = 8-output group. 1568 waves total
// (6/CU) vs 784 before; W reads are block-uniform scalar loads.
// ---------------------------------------------------------------------------
__global__ __launch_bounds__(128) void k_reduce(
    const float* __restrict__ x,  const float* __restrict__ Wr,
    const float* __restrict__ br, const float* __restrict__ gamma,
    const float* __restrict__ beta, const float* __restrict__ mean,
    const float* __restrict__ var, unsigned short* __restrict__ xrT)
{
    int t   = threadIdx.x;
    int pix = blockIdx.x * 128 + t;         // 0..12543
    int o0  = blockIdx.y * 8;
    int b   = pix / HW;
    int l   = pix - b * HW;
    const float* xb = x + (size_t)b * C_IN * HW + l;
    const float* W0 = Wr + (size_t)o0 * C_IN;

    float acc[8];
#pragma unroll
    for (int i = 0; i < 8; ++i) acc[i] = 0.f;

#pragma unroll 8
    for (int c = 0; c < C_IN; ++c) {
        float xv = xb[(size_t)c * HW];
#pragma unroll
        for (int i = 0; i < 8; ++i)
            acc[i] += W0[i * C_IN + c] * xv;
    }

    union { unsigned short s[8]; uint4 v; } pk;
#pragma unroll
    for (int i = 0; i < 8; ++i) {
        int o = o0 + i;
        float s  = gamma[o] * rsqrtf(var[o] + EPSV);
        float vv = (acc[i] + br[o] - mean[o]) * s + beta[o];
        pk.s[i] = f2bf(fmaxf(vv, 0.f));
    }
    *(uint4*)(xrT + (size_t)pix * 64 + o0) = pk.v;
}

// ---------------------------------------------------------------------------
// Kernel 2: per (h, g, b):
//   Phase A: kern[49][56] = Wspan_g[49][64] @ xr[64][56] + b_span (bf16 MFMA,
//            A/B fragments loaded straight from global — both L2-hot)
//   Phase B: out[c][w0..w0+3] = sum_k kern[k][w] * x[g*16+c][h+kh-3][w+kw-3]
// LDS = 39.5 KB -> 4 blocks/CU. One barrier.
// ---------------------------------------------------------------------------
#define KSTRIDE 60
__global__ __launch_bounds__(256) void k_invol(
    const float* __restrict__ x, const unsigned short* __restrict__ xrT,
    const float* __restrict__ Wspan, const float* __restrict__ bspan,
    float* __restrict__ out)
{
    __shared__ __align__(16) float s_x[GC_ * 434];          // [c][r0..6][col 0..61], 27776 B
    __shared__ __align__(16) float s_kern[49 * KSTRIDE];    // [k][w], 11760 B

    int h = blockIdx.x, g = blockIdx.y, b = blockIdx.z;
    int t = threadIdx.x;

    // ---- stage x tile: 16 ch x 7 rows x 62 cols, zero-padded borders ----
    {
        const float* xg = x + (size_t)(b * C_IN + g * GC_) * HW;
        for (int i = t; i < GC_ * 434; i += 256) {
            int c   = i / 434;
            int rem = i - c * 434;
            int r   = rem / 62;
            int wc  = rem - r * 62 - 3;
            int hr  = h + r - 3;
            float v = 0.f;
            if (hr >= 0 && hr < IMGH && wc >= 0 && wc < IMGW)
                v = xg[(size_t)c * HW + hr * IMGW + wc];
            s_x[i] = v;
        }
    }

    // ---- Phase A: MFMA kern = Wspan_g @ xr (fragments from global) ----
    {
        int wv = t >> 6, lane = t & 63;
        int ln = lane & 15, quad = lane >> 4;
        int m0 = wv * 16;

        int ko_a = m0 + ln;
        const float* wrow = Wspan + (size_t)(g * 49 + (ko_a < 49 ? ko_a : 48)) * 64;
        int pixbase = b * HW + h * IMGW;

        f32x4 acc[4];
#pragma unroll
        for (int nt = 0; nt < 4; ++nt) acc[nt] = (f32x4){0.f, 0.f, 0.f, 0.f};

#pragma unroll
        for (int ks = 0; ks < 2; ++ks) {
            int c0 = ks * 32 + quad * 8;
            // A fragment: 8 contiguous floats -> bf16
            union { unsigned short s[8]; bf16x8 v; } af;
#pragma unroll
            for (int j = 0; j < 8; ++j) af.s[j] = f2bf(wrow[c0 + j]);
#pragma unroll
            for (int nt = 0; nt < 4; ++nt) {
                int pix = pixbase + nt * 16 + ln;
                if (pix > 12543) pix = 12543;
                bf16x8 bb = *(const bf16x8*)(xrT + (size_t)pix * 64 + c0);
                acc[nt] = __builtin_amdgcn_mfma_f32_16x16x32_bf16(af.v, bb, acc[nt], 0, 0, 0);
            }
        }
        // C/D layout: col = lane&15, row = quad*4 + reg
#pragma unroll
        for (int r = 0; r < 4; ++r) {
            int ko = m0 + quad * 4 + r;
            float bias = bspan[g * 49 + (ko < 49 ? ko : 48)];
#pragma unroll
            for (int nt = 0; nt < 4; ++nt) {
                int w = nt * 16 + ln;
                if (ko < 49 && w < IMGW)
                    s_kern[ko * KSTRIDE + w] = acc[nt][r] + bias;
            }
        }
    }
    __syncthreads();

    // ---- Phase B: 224 threads = 14 w-quads x 16 channels; 4 outputs each ----
    if (t < 224) {
        int wq = t % 14, c = t / 14;
        int w0 = wq * 4;
        const float* sx = s_x + c * 434;
        float a0 = 0.f, a1 = 0.f, a2 = 0.f, a3 = 0.f;
#pragma unroll
        for (int r = 0; r < 7; ++r) {
            float xv[10];
#pragma unroll
            for (int j = 0; j < 10; ++j) xv[j] = sx[r * 62 + w0 + j];
#pragma unroll
            for (int dw = 0; dw < 7; ++dw) {
                float4 kv = *(const float4*)(s_kern + (r * 7 + dw) * KSTRIDE + w0);
                a0 += kv.x * xv[dw];
                a1 += kv.y * xv[dw + 1];
                a2 += kv.z * xv[dw + 2];
                a3 += kv.w * xv[dw + 3];
            }
        }
        float4 res = make_float4(a0, a1, a2, a3);
        *(float4*)(out + (size_t)(b * C_IN + g * GC_ + c) * HW + h * IMGW + w0) = res;
    }
}

// ---------------------------------------------------------------------------
extern "C" void kernel_launch(void* const* d_in, const int* in_sizes, int n_in,
                              void* d_out, int out_size, void* d_ws, size_t ws_size,
                              hipStream_t stream)
{
    const float* x   = (const float*)d_in[0];
    const float* Wr  = (const float*)d_in[1];
    const float* br  = (const float*)d_in[2];
    const float* gm  = (const float*)d_in[3];
    const float* bt  = (const float*)d_in[4];
    const float* mn  = (const float*)d_in[5];
    const float* vr  = (const float*)d_in[6];
    const float* Ws  = (const float*)d_in[7];
    const float* bs  = (const float*)d_in[8];
    float* out = (float*)d_out;

    unsigned short* xrT = (unsigned short*)d_ws;   // 12544 x 64 bf16 = 1.6 MB

    k_reduce<<<dim3(98, 8), 128, 0, stream>>>(x, Wr, br, gm, bt, mn, vr, xrT);
    k_invol<<<dim3(IMGW, G_, 4), 256, 0, stream>>>(x, xrT, Ws, bs, out);
}

// Round 3
// 124.639 us; speedup vs baseline: 1.9062x; 1.3134x over previous
//
#include <hip/hip_runtime.h>
#include <hip/hip_bf16.h>

#define HW    3136
#define C_IN  256
#define G_    16
#define GC_   16
#define IMGH  56
#define IMGW  56
#define EPSV  1e-5f

typedef __bf16 bf16x8 __attribute__((ext_vector_type(8)));
typedef float  f32x4  __attribute__((ext_vector_type(4)));

static __device__ __forceinline__ unsigned short f2bf(float f) {
    union { float f; unsigned u; } v; v.f = f;
    unsigned r = (v.u + 0x7FFFu + ((v.u >> 16) & 1u)) >> 16;   // RNE
    return (unsigned short)r;
}

static __device__ __forceinline__ bf16x8 pack8(const float* p) {
    union { unsigned short s[8]; bf16x8 v; } u;
#pragma unroll
    for (int j = 0; j < 8; ++j) u.s[j] = f2bf(p[j]);
    return u.v;
}

// ---------------------------------------------------------------------------
// Kernel 1: xrT[pix][o] = bf16(relu(BN(W_reduce @ x + b_reduce)))  via MFMA.
// M=64 outs, N=12544 pixels, K=256 ch. grid 196 x 256thr; wave = 16 pixels,
// all 64 outs. x read ONCE (12.8 MB). A/B fragments direct from global.
// ---------------------------------------------------------------------------
__global__ __launch_bounds__(256) void k_reduce(
    const float* __restrict__ x,  const float* __restrict__ Wr,
    const float* __restrict__ br, const float* __restrict__ gamma,
    const float* __restrict__ beta, const float* __restrict__ mean,
    const float* __restrict__ var, unsigned short* __restrict__ xrT)
{
    int t = threadIdx.x, wv = t >> 6, lane = t & 63;
    int ln = lane & 15, quad = lane >> 4;
    int p = blockIdx.x * 64 + wv * 16 + ln;        // pixel, 64 | 3136 so no b-straddle
    int b = p / HW, l = p - b * HW;
    const float* xb = x + (size_t)b * C_IN * HW + l;

    f32x4 acc[4];
#pragma unroll
    for (int mt = 0; mt < 4; ++mt) acc[mt] = (f32x4){0.f, 0.f, 0.f, 0.f};

#pragma unroll
    for (int ks = 0; ks < 8; ++ks) {
        int c0 = ks * 32 + quad * 8;
        // B fragment: x[c0..c0+7][p]  (8 channel-strided, lane-coalesced loads)
        float xv[8];
#pragma unroll
        for (int j = 0; j < 8; ++j) xv[j] = xb[(size_t)(c0 + j) * HW];
        union { unsigned short s[8]; bf16x8 v; } bfx;
#pragma unroll
        for (int j = 0; j < 8; ++j) bfx.s[j] = f2bf(xv[j]);
#pragma unroll
        for (int mt = 0; mt < 4; ++mt) {
            // A fragment: W[mt*16+ln][c0..c0+7], contiguous (L2-hot)
            bf16x8 af = pack8(Wr + (size_t)(mt * 16 + ln) * C_IN + c0);
            acc[mt] = __builtin_amdgcn_mfma_f32_16x16x32_bf16(af, bfx.v, acc[mt], 0, 0, 0);
        }
    }
    // D layout: col(pixel) = ln, row(out ch) = quad*4 + r
#pragma unroll
    for (int mt = 0; mt < 4; ++mt) {
        union { unsigned short s[4]; uint2 v; } pk;
#pragma unroll
        for (int r = 0; r < 4; ++r) {
            int o = mt * 16 + quad * 4 + r;
            float s  = gamma[o] * rsqrtf(var[o] + EPSV);
            float vv = (acc[mt][r] + br[o] - mean[o]) * s + beta[o];
            pk.s[r] = f2bf(fmaxf(vv, 0.f));
        }
        *(uint2*)(xrT + (size_t)p * 64 + mt * 16 + quad * 4) = pk.v;
    }
}

// ---------------------------------------------------------------------------
// Kernel 2: per block = (b, g, row-pair h0,h0+1), 512 threads.
//  swizzle: bid%8 -> XCD stripe of contiguous (b,row-pairs) => per-XCD L2
//  holds its ~2MB x working set.
//  order: issue x-tile loads to regs -> Phase A (MFMA kern, no LDS dep)
//         -> drain regs to LDS -> barrier -> Phase B.
// LDS = 56.3 KB -> 2 blocks/CU (16 waves/CU).
// ---------------------------------------------------------------------------
#define CSTRIDE 500    // words per channel in s_x (8 rows x 62 + 4 pad)
#define KSTR    124    // words per ko row in s_kern (2 rows x 60 + 4 pad)

__global__ __launch_bounds__(512) void k_invol(
    const float* __restrict__ x, const unsigned short* __restrict__ xrT,
    const float* __restrict__ Wspan, const float* __restrict__ bspan,
    float* __restrict__ out)
{
    __shared__ float s_x[GC_ * CSTRIDE];    // 32000 B
    __shared__ float s_kern[49 * KSTR];     // 24304 B

    int t = threadIdx.x;
    int bid = blockIdx.x;
    int xcd = bid & 7, jj = bid >> 3;          // 224 per xcd
    int g = jj & 15, rpb = jj >> 4;            // rpb in [0,14)
    int idx = xcd * 14 + rpb;                  // [0,112) = 4b x 28 row-pairs
    int b = idx / 28, rp = idx - b * 28;
    int h0 = rp * 2;

    // ---- issue x-tile loads into registers (16ch x 8 rows x 62 cols) ----
    const float* xg = x + (size_t)(b * C_IN + g * GC_) * HW;
    float xreg[16];
#pragma unroll
    for (int it = 0; it < 16; ++it) {
        int i = t + 512 * it;                  // < 8192, valid < 7936
        int c = i / 496;
        int rem = i - c * 496;
        int rr = rem / 62, col = rem - rr * 62;
        int hr = h0 + rr - 3, wc = col - 3;
        float v = 0.f;
        if (c < GC_ && hr >= 0 && hr < IMGH && wc >= 0 && wc < IMGW)
            v = xg[(size_t)c * HW + hr * IMGW + wc];
        xreg[it] = v;
    }

    // ---- Phase A: kern[49][112px] = Wspan_g @ xr + bias (MFMA, global frags)
    {
        int wv = t >> 6, lane = t & 63;
        int ln = lane & 15, quad = lane >> 4;
        int mt = wv & 3, nh = wv >> 2;         // 4 m-tiles x 2 n-halves
        int m0 = mt * 16;
        int ko_a = m0 + ln; if (ko_a > 48) ko_a = 48;
        const float* wrow = Wspan + (size_t)(g * 49 + ko_a) * 64;
        int pixbase = b * HW + h0 * IMGW;      // rows contiguous: gp = pixbase+pp

        f32x4 acc[4];
#pragma unroll
        for (int nt = 0; nt < 4; ++nt) acc[nt] = (f32x4){0.f, 0.f, 0.f, 0.f};

#pragma unroll
        for (int ks = 0; ks < 2; ++ks) {
            int c0 = ks * 32 + quad * 8;
            bf16x8 af = pack8(wrow + c0);
#pragma unroll
            for (int nt = 0; nt < 4; ++nt) {
                int pp = nh * 64 + nt * 16 + ln;
                if (pp > 111) pp = 111;
                bf16x8 bb = *(const bf16x8*)(xrT + (size_t)(pixbase + pp) * 64 + c0);
                acc[nt] = __builtin_amdgcn_mfma_f32_16x16x32_bf16(af, bb, acc[nt], 0, 0, 0);
            }
        }
#pragma unroll
        for (int r = 0; r < 4; ++r) {
            int ko = m0 + quad * 4 + r;
            float bias = bspan[g * 49 + (ko < 49 ? ko : 48)];
#pragma unroll
            for (int nt = 0; nt < 4; ++nt) {
                int pp = nh * 64 + nt * 16 + ln;
                if (ko < 49 && pp < 112) {
                    int prow = pp / 56, pw = pp - prow * 56;
                    s_kern[ko * KSTR + prow * 60 + pw] = acc[nt][r] + bias;
                }
            }
        }
    }

    // ---- drain x regs to LDS ----
#pragma unroll
    for (int it = 0; it < 16; ++it) {
        int i = t + 512 * it;
        int c = i / 496;
        int rem = i - c * 496;
        int rr = rem / 62, col = rem - rr * 62;
        if (c < GC_) s_x[c * CSTRIDE + rr * 62 + col] = xreg[it];
    }
    __syncthreads();

    // ---- Phase B: 448 thr = 2 rows x 14 w-quads x 16 ch; 4 outputs each ----
    if (t < 448) {
        int row = t / 224, rem = t - row * 224;
        int wq = rem % 14, c = rem / 14;
        int w0 = wq * 4;
        const float* sx = s_x + c * CSTRIDE + row * 62;
        const float* sk = s_kern + row * 60 + w0;
        float a0 = 0.f, a1 = 0.f, a2 = 0.f, a3 = 0.f;
#pragma unroll
        for (int r = 0; r < 7; ++r) {
            float xv[10];
#pragma unroll
            for (int q = 0; q < 10; ++q) xv[q] = sx[r * 62 + w0 + q];
#pragma unroll
            for (int dw = 0; dw < 7; ++dw) {
                float4 kv = *(const float4*)(sk + (r * 7 + dw) * KSTR);
                a0 += kv.x * xv[dw];
                a1 += kv.y * xv[dw + 1];
                a2 += kv.z * xv[dw + 2];
                a3 += kv.w * xv[dw + 3];
            }
        }
        *(float4*)(out + (size_t)(b * C_IN + g * GC_ + c) * HW
                       + (h0 + row) * IMGW + w0) = make_float4(a0, a1, a2, a3);
    }
}

// ---------------------------------------------------------------------------
extern "C" void kernel_launch(void* const* d_in, const int* in_sizes, int n_in,
                              void* d_out, int out_size, void* d_ws, size_t ws_size,
                              hipStream_t stream)
{
    const float* x   = (const float*)d_in[0];
    const float* Wr  = (const float*)d_in[1];
    const float* br  = (const float*)d_in[2];
    const float* gm  = (const float*)d_in[3];
    const float* bt  = (const float*)d_in[4];
    const float* mn  = (const float*)d_in[5];
    const float* vr  = (const float*)d_in[6];
    const float* Ws  = (const float*)d_in[7];
    const float* bs  = (const float*)d_in[8];
    float* out = (float*)d_out;

    unsigned short* xrT = (unsigned short*)d_ws;   // 12544 x 64 bf16 = 1.6 MB

    k_reduce<<<dim3(196), 256, 0, stream>>>(x, Wr, br, gm, bt, mn, vr, xrT);
    k_invol<<<dim3(1792), 512, 0, stream>>>(x, xrT, Ws, bs, out);
}